// Round 14
// baseline (290.746 us; speedup 1.0000x reference)
//
#include <hip/hip_runtime.h>
#include <stdint.h>

typedef __bf16 bf16x8 __attribute__((ext_vector_type(8)));
typedef __bf16 bf16x4 __attribute__((ext_vector_type(4)));
typedef float floatx4 __attribute__((ext_vector_type(4)));
typedef unsigned short ushort8v __attribute__((ext_vector_type(8)));
typedef unsigned int uint4v __attribute__((ext_vector_type(4)));
typedef unsigned short u16;
typedef unsigned long long u64;

#define GLOAD_LDS16(gp, lp)                                                       \
  __builtin_amdgcn_global_load_lds((__attribute__((address_space(1))) void*)(gp), \
                                   (__attribute__((address_space(3))) void*)(lp), \
                                   16, 0, 0)

__device__ __forceinline__ u16 f2bf(float f) {
  uint32_t u = __builtin_bit_cast(uint32_t, f);
  u = (u + 0x7FFFu + ((u >> 16) & 1u)) >> 16;  // RNE
  return (u16)u;
}

// 8 contiguous elements as bf16 bits. fp32 path: round-half-up + v_perm pack.
__device__ __forceinline__ ushort8v load8(const void* base, size_t elemOff, int isf32) {
  if (isf32) {
    const uint32_t* p = (const uint32_t*)base + elemOff;
    uint4v a = *(const uint4v*)p;
    uint4v b = *(const uint4v*)(p + 4);
#pragma unroll
    for (int i = 0; i < 4; ++i) { a[i] += 0x8000u; b[i] += 0x8000u; }
    uint4v r;
    r[0] = __builtin_amdgcn_perm(a[1], a[0], 0x07060302);
    r[1] = __builtin_amdgcn_perm(a[3], a[2], 0x07060302);
    r[2] = __builtin_amdgcn_perm(b[1], b[0], 0x07060302);
    r[3] = __builtin_amdgcn_perm(b[3], b[2], 0x07060302);
    return __builtin_bit_cast(ushort8v, r);
  }
  return *(const ushort8v*)((const u16*)base + elemOff);
}

// ---------------------------------------------------------------------------
// Device dtype probe (fallback path only; hot path self-detects inside prep).
__global__ void detect_dtype(const u16* __restrict__ q, int* __restrict__ flag) {
  if (threadIdx.x == 0) *flag = 0;
  __syncthreads();
  int hit = 0;
  for (int i = threadIdx.x; i < 8192; i += 256) {
    u16 u = q[i];
    if (((u >> 7) & 0xFF) == 0xFF) hit = 1;  // bf16 inf/NaN pattern -> fp32 data
  }
  if (hit) atomicOr(flag, 1);
}

// ---------------------------------------------------------------------------
// PREP (hot path), ROUND-14: W cvt + mask pack + dtype detect ONLY.
// The X conversion moved INTO gemm_qkv_b (reg-staged load8 on its idle VALU
// -- GEMM ran at 7% VALUBusy / 10% HBM). Removes ~73MB of prep HBM traffic
// (X f32 read 48MB + Xb write 25.6MB); GEMM adds ~22MB of L2-amortized reads.
//  blocks [0,2048):     W cvt (with detect; block 0 publishes flag)
//  blocks [2048,10240): mask pack, 4 words per warp
// ---------------------------------------------------------------------------
__global__ __launch_bounds__(256)
void prep(const void* X0,
          const void* W0, const void* W1, const void* W2, const void* W3,
          u16* __restrict__ Wb,
          const int* __restrict__ mask, u64* __restrict__ mpk,
          int* __restrict__ flagOut)
{
  const int id = blockIdx.x;
  const int t  = threadIdx.x;
  if (id < 2048) {
    // --- self-detect dtype from X0[0..8191] (same samples as old probe) ---
    __shared__ int sflag;
    if (t == 0) sflag = 0;
    int hit = 0;
    {
      const uint4v* q4 = (const uint4v*)X0;     // 8 u16 per uint4v
      const int base = t * 4;                   // 4 x uint4v = 32 u16/thread
#pragma unroll
      for (int i = 0; i < 4; ++i) {
        uint4v v = q4[base + i];
#pragma unroll
        for (int j = 0; j < 4; ++j) {
          const uint32_t w = v[j];
          if ((w & 0x7F80u) == 0x7F80u || (w & 0x7F800000u) == 0x7F800000u)
            hit = 1;                            // bf16 inf/NaN pattern -> fp32
        }
      }
    }
    __syncthreads();                            // sflag=0 visible
    if (hit) sflag = 1;                         // benign race: all write 1
    __syncthreads();
    const int isf = sflag;
    if (id == 0 && t == 0) *flagOut = isf;      // for gemm_qkv_b / gemm_out

    const int r2  = t >> 7;          // 0..1
    const int col = (t & 127) * 8;   // 0..1016
    const int s   = id >> 9;
    const void* src = (s == 0) ? W0 : (s == 1) ? W1 : (s == 2) ? W2 : W3;
    const int row = (id & 511) * 2 + r2;
    u16* dst = Wb + (size_t)s * 1024 * 1040 + (size_t)row * 1040 + col;
    *(ushort8v*)dst = load8(src, (size_t)row * 1024 + col, isf);
  } else {
    // mask [2][2048][2048] i32 -> bitmask [2*2048 rows][32 words] u64
    const int g    = (id - 2048) * 4 + (t >> 6);   // warp id, 4 words each
    const int lane = t & 63;
#pragma unroll
    for (int i = 0; i < 4; ++i) {
      const int wordId = g * 4 + i;                // 0..131071
      const int row  = wordId >> 5;
      const int word = wordId & 31;
      const int m = mask[(size_t)row * 2048 + word * 64 + lane];
      u64 bits = __ballot(m != 0);
      if (lane == 0) mpk[(size_t)row * 32 + word] = bits;
    }
  }
}

// mask pack standalone (fallback path only)
__global__ void pack_mask(const int* __restrict__ mask, u64* __restrict__ mpk) {
  const int gw   = (blockIdx.x * 256 + threadIdx.x) >> 6;
  const int lane = threadIdx.x & 63;
  const int word = gw & 31;
  const int row  = gw >> 5;
  const int m = mask[(size_t)row * 2048 + word * 64 + lane];
  u64 bits = __ballot(m != 0);
  if (lane == 0) mpk[(size_t)row * 32 + word] = bits;
}

// weights -> bf16 unpadded (fallback path only)
__global__ __launch_bounds__(256)
void cvt_w(const void* W0, const void* W1, const void* W2, const void* W3,
           u16* __restrict__ dst, const int* __restrict__ flagp) {
  const int isf = *flagp;
  const int z = blockIdx.y;
  const void* src = (z == 0) ? W0 : (z == 1) ? W1 : (z == 2) ? W2 : W3;
  const size_t off = ((size_t)blockIdx.x * 256 + threadIdx.x) * 8;
  *(ushort8v*)(dst + (size_t)z * 1024 * 1024 + off) = load8(src, off, isf);
}

// ---------------------------------------------------------------------------
// HOT QKV GEMM, ROUND-14: A read DIRECTLY from X (fp32/bf16) with in-kernel
// conversion on the idle VALU. A reg-staged (load8 issued TWO kt ahead,
// ~2600cy cover) -> ds_write_b128 into dbuf LDS; W via GLOAD from padded Wb.
// SINGLE barrier preserved: ds_write A(kt+1)->buf^1 races only with iter
// kt-1's readers of buf^1, which completed (lgkmcnt) before the previous
// barrier; the end-of-kt barrier publishes writes + drains W's GLOAD.
// 128x128 tile, BK=32, LDS 32 KB. Grid (32,8,3): same-x blocks (A sharers)
// land on one XCD -> X f32 panels L2-amortized.
// z=0->Qb (x 0.125*log2e), z=1->Kb, z=2->Vt (barrier-free private transpose).
// ---------------------------------------------------------------------------
__global__ __launch_bounds__(256, 3)
void gemm_qkv_b(const void* X0, const void* X1, const void* X2,
                const u16* __restrict__ Wb,
                u16* __restrict__ Qb, u16* __restrict__ Kb, u16* __restrict__ Vt,
                const int* __restrict__ flagp)
{
  const int WS = 1040, N = 1024, K = 1024;
  const int z = blockIdx.z;
  const void* A_ = (z == 0) ? X0 : (z == 1) ? X1 : X2;
  const u16* W = Wb + (size_t)z * 1024 * WS;
  const int isf = *flagp;

  __shared__ __align__(16) u16 lS[4 * 128 * 32];   // 32KB: lA dbuf | lB dbuf
  u16* lA = lS;
  u16* lB = lS + 8192;

  const int tid  = threadIdx.x;
  const int lane = tid & 63;
  const int quad = lane >> 4;
  const int l15  = lane & 15;
  const int w    = tid >> 6;
  const int wm   = w >> 1, wn = w & 1;
  const int tileM = blockIdx.x * 128;
  const int tileN = blockIdx.y * 128;

  floatx4 acc[4][4] = {};

  const int ldRow = tid >> 2;        // 0..63
  const int ldCol = (tid & 3) * 8;   // 0,8,16,24
  const size_t aOff = (size_t)(tileM + ldRow) * 1024 + ldCol;   // X stride 1024
  const u16* bG = W + (size_t)(tileN + ldRow) * WS + ldCol;
  u16* lAp = lA + tid * 8;           // linear LDS, row-major [128][32]
  u16* lBp = lB + tid * 8;

  // prologue: stage tile 0 (A via regs, W via GLOAD); preload tile-1 A regs
  ushort8v a0 = load8(A_, aOff, isf);
  ushort8v a1 = load8(A_, aOff + (size_t)64 * 1024, isf);
  *(ushort8v*)lAp          = a0;
  *(ushort8v*)(lAp + 2048) = a1;
  GLOAD_LDS16(bG, lBp);
  GLOAD_LDS16(bG + (size_t)64 * WS, lBp + 2048);
  a0 = load8(A_, aOff + 32, isf);
  a1 = load8(A_, aOff + (size_t)64 * 1024 + 32, isf);
  __syncthreads();

#pragma unroll 2
  for (int k0 = 0; k0 < K; k0 += 32) {
    const int cur = (k0 >> 5) & 1;
    const int nxo = 4096 * (cur ^ 1);
    if (k0 + 32 < K) {               // stage tile kt+1 into the other buffer
      *(ushort8v*)(lAp + nxo)        = a0;
      *(ushort8v*)(lAp + nxo + 2048) = a1;
      GLOAD_LDS16(bG + k0 + 32, lBp + nxo);
      GLOAD_LDS16(bG + (size_t)64 * WS + k0 + 32, lBp + nxo + 2048);
    }
    if (k0 + 64 < K) {               // prefetch tile kt+2 A into registers
      a0 = load8(A_, aOff + k0 + 64, isf);
      a1 = load8(A_, aOff + (size_t)64 * 1024 + k0 + 64, isf);
    }
    const u16* cA = lA + 4096 * cur;
    const u16* cB = lB + 4096 * cur;
    bf16x8 af[4], bw[4];
#pragma unroll
    for (int i = 0; i < 4; ++i) {
      af[i] = *(const bf16x8*)&cA[(wm * 64 + i * 16 + l15) * 32 + quad * 8];
      bw[i] = *(const bf16x8*)&cB[(wn * 64 + i * 16 + l15) * 32 + quad * 8];
    }
#pragma unroll
    for (int i = 0; i < 4; ++i)
#pragma unroll
      for (int j = 0; j < 4; ++j)
        acc[i][j] = __builtin_amdgcn_mfma_f32_16x16x32_bf16(af[i], bw[j], acc[i][j], 0, 0, 0);
    __syncthreads();                 // publishes A writes, drains W GLOAD
  }

  if (z < 2) {
    u16* C = (z == 0) ? Qb : Kb;
    // z==0: fold 1/sqrt(Dh) * log2(e) into Q (attn uses exp2 directly)
    const float sc = (z == 0) ? 0.18033688011112042f : 1.0f;
#pragma unroll
    for (int i = 0; i < 4; ++i) {
      const int row0 = tileM + wm * 64 + i * 16 + quad * 4;
#pragma unroll
      for (int j = 0; j < 4; ++j) {
        const int col = tileN + wn * 64 + j * 16 + l15;
#pragma unroll
        for (int r = 0; r < 4; ++r)
          C[(size_t)(row0 + r) * N + col] = f2bf(acc[i][j][r] * sc);
      }
    }
  } else {
    // transpose 64x64 wave-tiles through PRIVATE LDS regions (XOR-swizzled).
    // All waves passed the K-loop's final barrier -> lS free; each wave
    // writes/reads ONLY its own 4096-u16 region -> no barriers at all.
    u16* myT = lS + w * 4096;
#pragma unroll
    for (int i = 0; i < 4; ++i)
#pragma unroll
      for (int j = 0; j < 4; ++j)
#pragma unroll
        for (int r = 0; r < 4; ++r) {
          const int lr = i * 16 + quad * 4 + r;
          const int lc = j * 16 + l15;
          myT[lr * 64 + (lc ^ (quad << 4))] = f2bf(acc[i][j][r]);
        }
    {
      const int n    = lane;
      const int gcol = tileN + wn * 64 + n;      // = h*64 + d
      const int hh = gcol >> 6, dd = gcol & 63;
      const int growBase = tileM + wm * 64;      // = b*2048 + s0
      const int bb = growBase >> 11;
      const int s0 = growBase & 2047;
      u16* dst = Vt + (((size_t)bb * 16 + hh) * 64 + dd) * 2048 + s0;
#pragma unroll
      for (int m0 = 0; m0 < 64; m0 += 8) {
        ushort8v pk;
#pragma unroll
        for (int t = 0; t < 8; ++t) {
          const int m = m0 + t;
          pk[t] = myT[m * 64 + (n ^ ((m & 12) << 2))];
        }
        *(ushort8v*)(dst + m0) = pk;
      }
    }
  }
}

// ---------------------------------------------------------------------------
// FALLBACK QKV GEMM: fp32/bf16 A via load8 + register prefetch, bf16 W
// (unpadded). Used only when ws_size is too small.
// ---------------------------------------------------------------------------
__global__ __launch_bounds__(256)
void gemm_qkv_f(const void* X0, const void* X1, const void* X2,
                const u16* __restrict__ Wb,
                u16* __restrict__ Qb, u16* __restrict__ Kb, u16* __restrict__ Vt,
                const int* __restrict__ flagp)
{
  const int K = 1024, N = 1024;
  const int isf = *flagp;
  const int z = blockIdx.z;
  const void* A_ = (z == 0) ? X0 : (z == 1) ? X1 : X2;
  const u16* W = Wb + (size_t)z * 1024 * 1024;

  __shared__ __align__(16) u16 lA[128 * 32];
  __shared__ __align__(16) u16 lB[128 * 32];

  const int tid  = threadIdx.x;
  const int lane = tid & 63;
  const int quad = lane >> 4;
  const int l15  = lane & 15;
  const int w    = tid >> 6;
  const int wm   = w >> 1, wn = w & 1;
  const int tileM = blockIdx.x * 128;
  const int tileN = blockIdx.y * 128;

  floatx4 acc[4][4] = {};

  const int ldRow = tid >> 2;
  const int ldCol = (tid & 3) * 8;
  const size_t aOff = (size_t)(tileM + ldRow) * K + ldCol;
  const u16* bG = W + (size_t)(tileN + ldRow) * K + ldCol;
  u16* lAp = lA + tid * 8;
  u16* lBp = lB + tid * 8;

  ushort8v a0 = load8(A_, aOff, isf);
  ushort8v a1 = load8(A_, aOff + (size_t)64 * K, isf);
  ushort8v b0 = *(const ushort8v*)bG;
  ushort8v b1 = *(const ushort8v*)(bG + (size_t)64 * K);

  for (int k0 = 0; k0 < K; k0 += 32) {
    __syncthreads();
    *(ushort8v*)lAp          = a0;
    *(ushort8v*)(lAp + 2048) = a1;
    *(ushort8v*)lBp          = b0;
    *(ushort8v*)(lBp + 2048) = b1;
    __syncthreads();

    if (k0 + 32 < K) {
      a0 = load8(A_, aOff + k0 + 32, isf);
      a1 = load8(A_, aOff + (size_t)64 * K + k0 + 32, isf);
      b0 = *(const ushort8v*)(bG + k0 + 32);
      b1 = *(const ushort8v*)(bG + (size_t)64 * K + k0 + 32);
    }

    bf16x8 af[4], bw[4];
#pragma unroll
    for (int i = 0; i < 4; ++i) {
      af[i] = *(const bf16x8*)&lA[(wm * 64 + i * 16 + l15) * 32 + quad * 8];
      bw[i] = *(const bf16x8*)&lB[(wn * 64 + i * 16 + l15) * 32 + quad * 8];
    }
#pragma unroll
    for (int i = 0; i < 4; ++i)
#pragma unroll
      for (int j = 0; j < 4; ++j)
        acc[i][j] = __builtin_amdgcn_mfma_f32_16x16x32_bf16(af[i], bw[j], acc[i][j], 0, 0, 0);
  }

  if (z < 2) {
    u16* C = (z == 0) ? Qb : Kb;
    const float sc = (z == 0) ? 0.18033688011112042f : 1.0f;
#pragma unroll
    for (int i = 0; i < 4; ++i) {
      const int row0 = tileM + wm * 64 + i * 16 + quad * 4;
#pragma unroll
      for (int j = 0; j < 4; ++j) {
        const int col = tileN + wn * 64 + j * 16 + l15;
#pragma unroll
        for (int r = 0; r < 4; ++r)
          C[(size_t)(row0 + r) * N + col] = f2bf(acc[i][j][r] * sc);
      }
    }
  } else {
    const int half = w >> 1;
    u16* myT = (w & 1) ? lB : lA;
#pragma unroll
    for (int pass = 0; pass < 2; ++pass) {
      __syncthreads();
      if (half == pass) {
#pragma unroll
        for (int i = 0; i < 4; ++i)
#pragma unroll
          for (int j = 0; j < 4; ++j)
#pragma unroll
            for (int r = 0; r < 4; ++r) {
              const int lr = i * 16 + quad * 4 + r;
              const int lc = j * 16 + l15;
              myT[lr * 64 + (lc ^ (quad << 4))] = f2bf(acc[i][j][r]);
            }
      }
      __syncthreads();
      if (half == pass) {
        const int n    = lane;
        const int gcol = tileN + wn * 64 + n;
        const int hh = gcol >> 6, dd = gcol & 63;
        const int growBase = tileM + wm * 64;
        const int bb = growBase >> 11;
        const int s0 = growBase & 2047;
        u16* dst = Vt + (((size_t)bb * 16 + hh) * 64 + dd) * 2048 + s0;
#pragma unroll
        for (int m0 = 0; m0 < 64; m0 += 8) {
          ushort8v pk;
#pragma unroll
          for (int t = 0; t < 8; ++t) {
            const int m = m0 + t;
            pk[t] = myT[m * 64 + (n ^ ((m & 12) << 2))];
          }
          *(ushort8v*)(dst + m0) = pk;
        }
      }
    }
  }
}

// ---------------------------------------------------------------------------
// Flash attention, no-max exp2 softmax. FROZEN at the r9/r10 plateau:
// QBLK=128, single barrier/kt, K/V dbuf, warp-private P. Six structures
// (2/1-barrier, QBLK 64/128, 8-32 waves/CU, setprio, pipelined-P) all land
// at 71+-3us (VALU ~50 / MFMA ~22) -> structural plateau for this family.
// ---------------------------------------------------------------------------
__global__ __launch_bounds__(256)
void attn(const u16* Qb, const u16* __restrict__ Kb, const u16* __restrict__ Vt,
          const u64* __restrict__ mpk, u16* AO, int aoStr)
{
  __shared__ __align__(16) u16 lK[2][64 * 64];
  __shared__ __align__(16) u16 lV[2][64 * 64];
  __shared__ __align__(16) u16 lP[4][32 * 64];

  const int tid  = threadIdx.x;
  const int lane = tid & 63;
  const int quad = lane >> 4;
  const int l15  = lane & 15;
  const int w    = tid >> 6;

  const int bh = blockIdx.x;
  const int qt = blockIdx.y;
  const int b  = bh >> 4;
  const int h  = bh & 15;
  const size_t rowB   = (size_t)b * 2048;
  const size_t vtBase = ((size_t)bh * 64) * 2048;
  const int qbase = qt * 128 + w * 32;     // this warp's 32 q-rows

  bf16x8 aq[2][2];                         // [q-group][k-half]
#pragma unroll
  for (int g = 0; g < 2; ++g) {
    const u16* qp = Qb + (rowB + qbase + g * 16 + l15) * 1024 + h * 64 + quad * 8;
    aq[g][0] = *(const bf16x8*)qp;
    aq[g][1] = *(const bf16x8*)(qp + 32);
  }

  const ushort8v one_u = {0x3F80, 0x3F80, 0x3F80, 0x3F80, 0x3F80, 0x3F80, 0x3F80, 0x3F80};
  const bf16x8 ones = __builtin_bit_cast(bf16x8, one_u);

  floatx4 o[2][4];
  floatx4 l4[2];
#pragma unroll
  for (int g = 0; g < 2; ++g) {
    l4[g] = (floatx4){0.f, 0.f, 0.f, 0.f};
#pragma unroll
    for (int nb = 0; nb < 4; ++nb) o[g][nb] = (floatx4){0.f, 0.f, 0.f, 0.f};
  }

  // swapped QK^T: lane's q-rows are qbase + g*16 + l15 -> one mask word per g
  const u64* mrow0 = mpk + (rowB + qbase + l15) * 32;
  const u64* mrow1 = mpk + (rowB + qbase + 16 + l15) * 32;
  u16* lPw = &lP[w][0];              // per-warp [32 q][64 k]

  // staging: row = tid>>3, col16 = tid&7; source col pre-XOR'd so swizzled
  // reads see logical LDS[r][c] = M[r][c ^ ((r&7)<<3)] (u16 units).
  const int r1 = tid >> 3;
  const int cs = ((tid & 7) ^ (r1 & 7)) * 8;
  const u16* kSrc = Kb + (rowB + r1) * 1024 + h * 64 + cs;
  const u16* vSrc = Vt + vtBase + (size_t)r1 * 2048 + cs;

  // prologue: K(0),V(0) -> buffer 0 (drained by the kt=0 barrier)
  GLOAD_LDS16(kSrc,                     &lK[0][tid * 8]);
  GLOAD_LDS16(kSrc + (size_t)32 * 1024, &lK[0][tid * 8 + 2048]);
  GLOAD_LDS16(vSrc,                     &lV[0][tid * 8]);
  GLOAD_LDS16(vSrc + (size_t)32 * 2048, &lV[0][tid * 8 + 2048]);

#pragma unroll 2
  for (int kt = 0; kt < 32; ++kt) {
    const int cur = kt & 1;
    __syncthreads();                 // drains buf[cur] DMA; all waves finished
                                     // reading buf[cur^1] last iter -> WAR safe
    if (kt < 31) {                   // prefetch kt+1; lands during this compute
      const u16* kS = kSrc + (size_t)(kt + 1) * 64 * 1024;
      const u16* vS = vSrc + (kt + 1) * 64;
      GLOAD_LDS16(kS,                     &lK[cur ^ 1][tid * 8]);
      GLOAD_LDS16(kS + (size_t)32 * 1024, &lK[cur ^ 1][tid * 8 + 2048]);
      GLOAD_LDS16(vS,                     &lV[cur ^ 1][tid * 8]);
      GLOAD_LDS16(vS + (size_t)32 * 2048, &lV[cur ^ 1][tid * 8 + 2048]);
    }

    const u64 mw0 = mrow0[kt];
    const u64 mw1 = mrow1[kt];

#pragma unroll
    for (int nb = 0; nb < 4; ++nb) {
      const int row = nb * 16 + l15;
      const int swk = (row & 7) << 3;
      // A = K rows (shared across both q-groups), B = Q (registers)
      bf16x8 ak0 = *(const bf16x8*)&lK[cur][row * 64 + ((quad * 8) ^ swk)];
      bf16x8 ak1 = *(const bf16x8*)&lK[cur][row * 64 + ((quad * 8 + 32) ^ swk)];
      floatx4 s0 = {0.f, 0.f, 0.f, 0.f};
      floatx4 s1 = {0.f, 0.f, 0.f, 0.f};
      s0 = __builtin_amdgcn_mfma_f32_16x16x32_bf16(ak0, aq[0][0], s0, 0, 0, 0);
      s1 = __builtin_amdgcn_mfma_f32_16x16x32_bf16(ak0, aq[1][0], s1, 0, 0, 0);
      s0 = __builtin_amdgcn_mfma_f32_16x16x32_bf16(ak1, aq[0][1], s0, 0, 0, 0);
      s1 = __builtin_amdgcn_mfma_f32_16x16x32_bf16(ak1, aq[1][1], s1, 0, 0, 0);
      // S^T[k = nb*16+quad*4+r][q]; mask bits are k-consecutive
      const int kb = nb * 16 + quad * 4;
      const uint32_t nib0 = (uint32_t)(mw0 >> kb) & 0xFu;
      const uint32_t nib1 = (uint32_t)(mw1 >> kb) & 0xFu;
      const float a0 = (nib0 & 1u) ? __builtin_amdgcn_exp2f(s0[0]) : 0.0f;
      const float a1 = (nib0 & 2u) ? __builtin_amdgcn_exp2f(s0[1]) : 0.0f;
      const float a2 = (nib0 & 4u) ? __builtin_amdgcn_exp2f(s0[2]) : 0.0f;
      const float a3 = (nib0 & 8u) ? __builtin_amdgcn_exp2f(s0[3]) : 0.0f;
      const float c0 = (nib1 & 1u) ? __builtin_amdgcn_exp2f(s1[0]) : 0.0f;
      const float c1 = (nib1 & 2u) ? __builtin_amdgcn_exp2f(s1[1]) : 0.0f;
      const float c2 = (nib1 & 4u) ? __builtin_amdgcn_exp2f(s1[2]) : 0.0f;
      const float c3 = (nib1 & 8u) ? __builtin_amdgcn_exp2f(s1[3]) : 0.0f;
      bf16x4 p0, p1;
      p0[0] = (__bf16)a0; p0[1] = (__bf16)a1;   // v_cvt_pk_bf16_f32 (RNE)
      p0[2] = (__bf16)a2; p0[3] = (__bf16)a3;
      p1[0] = (__bf16)c0; p1[1] = (__bf16)c1;
      p1[2] = (__bf16)c2; p1[3] = (__bf16)c3;
      const int col = kb ^ ((l15 & 7) << 3);
      *(bf16x4*)&lPw[l15 * 64 + col]        = p0;   // ds_write_b64
      *(bf16x4*)&lPw[(16 + l15) * 64 + col] = p1;
    }
    // no barrier: P is warp-private; same-wave DS ordering covers write->read

#pragma unroll
    for (int ks = 0; ks < 2; ++ks) {
      const int pc = (ks * 32 + quad * 8) ^ ((l15 & 7) << 3);
      bf16x8 ap0 = *(const bf16x8*)&lPw[l15 * 64 + pc];
      bf16x8 ap1 = *(const bf16x8*)&lPw[(16 + l15) * 64 + pc];
#pragma unroll
      for (int nb = 0; nb < 4; ++nb) {
        const int row = nb * 16 + l15;
        bf16x8 bv = *(const bf16x8*)&lV[cur][row * 64 + ((ks * 32 + quad * 8) ^ ((row & 7) << 3))];
        o[0][nb] = __builtin_amdgcn_mfma_f32_16x16x32_bf16(ap0, bv, o[0][nb], 0, 0, 0);
        o[1][nb] = __builtin_amdgcn_mfma_f32_16x16x32_bf16(ap1, bv, o[1][nb], 0, 0, 0);
      }
      l4[0] = __builtin_amdgcn_mfma_f32_16x16x32_bf16(ap0, ones, l4[0], 0, 0, 0);
      l4[1] = __builtin_amdgcn_mfma_f32_16x16x32_bf16(ap1, ones, l4[1], 0, 0, 0);
    }
  }

#pragma unroll
  for (int g = 0; g < 2; ++g)
#pragma unroll
    for (int r = 0; r < 4; ++r) {
      const float inv = 1.0f / l4[g][r];
      const size_t orow = (rowB + qbase + g * 16 + quad * 4 + r) * aoStr + h * 64;
#pragma unroll
      for (int nb = 0; nb < 4; ++nb)
        AO[orow + nb * 16 + l15] = f2bf(o[g][nb][r] * inv);
    }
}

// ---------------------------------------------------------------------------
// Output projection: 64x64 tile, grid (64,16) = 1024 blocks = 4 blocks/CU.
// Latency-bound 2-phase kernel; same-x blocks share the A panel and land on
// one XCD (linear id = x + 64y => id mod 8 == x mod 8) -> L2 A-reuse.
// ---------------------------------------------------------------------------
__global__ __launch_bounds__(256, 4)
void gemm_out(const u16* __restrict__ A, int aStr,
              const u16* __restrict__ W, int wStr, void* C_,
              const int* __restrict__ flagp)
{
  const int K = 1024, N = 1024;
  const int isf = *flagp;

  __shared__ __align__(16) u16 lA[2 * 64 * 32];
  __shared__ __align__(16) u16 lB[2 * 64 * 32];

  const int tid  = threadIdx.x;
  const int lane = tid & 63;
  const int quad = lane >> 4;
  const int l15  = lane & 15;
  const int w    = tid >> 6;
  const int tileM = blockIdx.x * 64;
  const int tileN = blockIdx.y * 64;

  floatx4 acc[4] = {};

  const int ldRow = tid >> 2;
  const int ldCol = (tid & 3) * 8;
  const u16* aG = A + (size_t)(tileM + ldRow) * aStr + ldCol;
  const u16* bG = W + (size_t)(tileN + ldRow) * wStr + ldCol;
  u16* lAp = lA + tid * 8;
  u16* lBp = lB + tid * 8;

  // prologue: stage tile 0 into buffer 0
  GLOAD_LDS16(aG, lAp);
  GLOAD_LDS16(bG, lBp);
  __syncthreads();

#pragma unroll 2
  for (int k0 = 0; k0 < K; k0 += 32) {
    const int cur = (k0 >> 5) & 1;
    const int nx = 2048 * (cur ^ 1);
    if (k0 + 32 < K) {
      GLOAD_LDS16(aG + k0 + 32, lAp + nx);
      GLOAD_LDS16(bG + k0 + 32, lBp + nx);
    }
    const u16* cA = lA + 2048 * cur;
    const u16* cB = lB + 2048 * cur;
    bf16x8 af[4], bw;
#pragma unroll
    for (int i = 0; i < 4; ++i)
      af[i] = *(const bf16x8*)&cA[(i * 16 + l15) * 32 + quad * 8];
    bw = *(const bf16x8*)&cB[(w * 16 + l15) * 32 + quad * 8];
#pragma unroll
    for (int i = 0; i < 4; ++i)
      acc[i] = __builtin_amdgcn_mfma_f32_16x16x32_bf16(af[i], bw, acc[i], 0, 0, 0);
    __syncthreads();
  }

#pragma unroll
  for (int i = 0; i < 4; ++i) {
    const int row0 = tileM + i * 16 + quad * 4;
    const int col  = tileN + w * 16 + l15;
#pragma unroll
    for (int r = 0; r < 4; ++r) {
      const size_t off = (size_t)(row0 + r) * N + col;
      if (isf) ((float*)C_)[off] = acc[i][r];
      else     ((u16*)C_)[off]   = f2bf(acc[i][r]);
    }
  }
}

// ---------------------------------------------------------------------------
extern "C" void kernel_launch(void* const* d_in, const int* in_sizes, int n_in,
                              void* d_out, int out_size, void* d_ws, size_t ws_size,
                              hipStream_t stream)
{
  const int* mk = (const int*)d_in[3];

  // ws: [flag 256B][mpk 1MB][Qb 8MB][Kb 8MB][Vt 8MB][Wb pad 8.5MB][AO pad 25.6MB]
  int* flag = (int*)d_ws;
  u64* mpk  = (u64*)((char*)d_ws + 256);
  const size_t SZ = (size_t)4096 * 1024;
  u16* Qb = (u16*)((char*)d_ws + 256 + (size_t)1048576);
  u16* Kb = Qb + SZ;
  u16* Vt = Kb + SZ;
  u16* Wb = Vt + SZ;

  const size_t WB_PAD = (size_t)4 * 1024 * 1040;
  const size_t XB_PAD = (size_t)3 * 4096 * 1040;
  const size_t NEED = 256 + 1048576 + 3 * SZ * 2 + WB_PAD * 2 + XB_PAD * 2;

  if (ws_size >= NEED) {
    // HOT PATH: 4 dispatches. prep = W cvt + mask + detect;
    // X conversion folded into gemm_qkv_b (idle-VALU conversion).
    u16* AOp = Wb + WB_PAD;   // former Xb slot, now attn-output scratch
    prep<<<10240, 256, 0, stream>>>(d_in[0],
                                    d_in[4], d_in[5], d_in[6], d_in[7],
                                    Wb, mk, mpk, flag);
    gemm_qkv_b<<<dim3(32, 8, 3), 256, 0, stream>>>(d_in[0], d_in[1], d_in[2],
                                                   Wb, Qb, Kb, Vt, flag);
    attn<<<dim3(32, 16), 256, 0, stream>>>(Qb, Kb, Vt, mpk, AOp, 1040);
    gemm_out<<<dim3(64, 16), 256, 0, stream>>>(AOp, 1040,
                                               Wb + (size_t)3 * 1024 * 1040, 1040,
                                               d_out, flag);
  } else {
    // FALLBACK (proven at 33.3 MB ws)
    detect_dtype<<<1, 256, 0, stream>>>((const u16*)d_in[0], flag);
    pack_mask<<<32768, 256, 0, stream>>>(mk, mpk);
    cvt_w<<<dim3(512, 4), 256, 0, stream>>>(d_in[4], d_in[5], d_in[6], d_in[7], Wb, flag);
    gemm_qkv_f<<<dim3(32, 8, 3), 256, 0, stream>>>(d_in[0], d_in[1], d_in[2],
                                                   Wb, Qb, Kb, Vt, flag);
    attn<<<dim3(32, 16), 256, 0, stream>>>(Qb, Kb, Vt, mpk, Qb, 1024);
    gemm_out<<<dim3(64, 16), 256, 0, stream>>>(Qb, 1024,
                                               Wb + (size_t)3 * 1024 * 1024, 1024,
                                               d_out, flag);
  }
}

// Round 15
// 268.487 us; speedup vs baseline: 1.0829x; 1.0829x over previous
//
#include <hip/hip_runtime.h>
#include <stdint.h>

typedef __bf16 bf16x8 __attribute__((ext_vector_type(8)));
typedef __bf16 bf16x4 __attribute__((ext_vector_type(4)));
typedef float floatx4 __attribute__((ext_vector_type(4)));
typedef unsigned short ushort8v __attribute__((ext_vector_type(8)));
typedef unsigned int uint4v __attribute__((ext_vector_type(4)));
typedef unsigned short u16;
typedef unsigned long long u64;

#define GLOAD_LDS16(gp, lp)                                                       \
  __builtin_amdgcn_global_load_lds((__attribute__((address_space(1))) void*)(gp), \
                                   (__attribute__((address_space(3))) void*)(lp), \
                                   16, 0, 0)

__device__ __forceinline__ u16 f2bf(float f) {
  uint32_t u = __builtin_bit_cast(uint32_t, f);
  u = (u + 0x7FFFu + ((u >> 16) & 1u)) >> 16;  // RNE
  return (u16)u;
}

// 8 contiguous elements as bf16 bits. fp32 path: round-half-up + v_perm pack.
__device__ __forceinline__ ushort8v load8(const void* base, size_t elemOff, int isf32) {
  if (isf32) {
    const uint32_t* p = (const uint32_t*)base + elemOff;
    uint4v a = *(const uint4v*)p;
    uint4v b = *(const uint4v*)(p + 4);
#pragma unroll
    for (int i = 0; i < 4; ++i) { a[i] += 0x8000u; b[i] += 0x8000u; }
    uint4v r;
    r[0] = __builtin_amdgcn_perm(a[1], a[0], 0x07060302);
    r[1] = __builtin_amdgcn_perm(a[3], a[2], 0x07060302);
    r[2] = __builtin_amdgcn_perm(b[1], b[0], 0x07060302);
    r[3] = __builtin_amdgcn_perm(b[3], b[2], 0x07060302);
    return __builtin_bit_cast(ushort8v, r);
  }
  return *(const ushort8v*)((const u16*)base + elemOff);
}

// ---------------------------------------------------------------------------
// Device dtype probe (fallback path only; hot path self-detects inside prep).
__global__ void detect_dtype(const u16* __restrict__ q, int* __restrict__ flag) {
  if (threadIdx.x == 0) *flag = 0;
  __syncthreads();
  int hit = 0;
  for (int i = threadIdx.x; i < 8192; i += 256) {
    u16 u = q[i];
    if (((u >> 7) & 0xFF) == 0xFF) hit = 1;  // bf16 inf/NaN pattern -> fp32 data
  }
  if (hit) atomicOr(flag, 1);
}

// ---------------------------------------------------------------------------
// FUSED PREP (hot path): bf16 conversion of X0..X2/W0..W3 into padded
// (stride 1040) buffers + mask bit-packing + dtype self-detection.
// ROUND-15: r13 structure RESTORED (best: 268.6us). Both work-movement
// experiments refuted: r12 riders (serial tail after GEMM blocks) and r14
// X-fold (reg-staged load8 re-exposed VMEM latency the GLOAD DMA hides;
// FETCH showed L2 amortization worked but dur 50->82us anyway).
//  blocks [0,6144):      X cvt (with detect)
//  blocks [6144,8192):   W cvt (with detect)
//  blocks [8192,16384):  mask pack, 4 words per warp
// ---------------------------------------------------------------------------
__global__ __launch_bounds__(256)
void prep(const void* X0, const void* X1, const void* X2,
          const void* W0, const void* W1, const void* W2, const void* W3,
          u16* __restrict__ Xb, u16* __restrict__ Wb,
          const int* __restrict__ mask, u64* __restrict__ mpk,
          int* __restrict__ flagOut)
{
  const int id = blockIdx.x;
  const int t  = threadIdx.x;
  if (id < 8192) {
    // --- self-detect dtype from X0[0..8191] (same samples as old probe) ---
    __shared__ int sflag;
    if (t == 0) sflag = 0;
    int hit = 0;
    {
      const uint4v* q4 = (const uint4v*)X0;     // 8 u16 per uint4v
      const int base = t * 4;                   // 4 x uint4v = 32 u16/thread
#pragma unroll
      for (int i = 0; i < 4; ++i) {
        uint4v v = q4[base + i];
#pragma unroll
        for (int j = 0; j < 4; ++j) {
          const uint32_t w = v[j];
          if ((w & 0x7F80u) == 0x7F80u || (w & 0x7F800000u) == 0x7F800000u)
            hit = 1;                            // bf16 inf/NaN pattern -> fp32
        }
      }
    }
    __syncthreads();                            // sflag=0 visible
    if (hit) sflag = 1;                         // benign race: all write 1
    __syncthreads();
    const int isf = sflag;
    if (id == 0 && t == 0) *flagOut = isf;      // for gemm_out (later dispatch)

    const int r2  = t >> 7;          // 0..1
    const int col = (t & 127) * 8;   // 0..1016
    const void* src; u16* dst; int row;
    if (id < 6144) {
      const int s = id >> 11;
      src = (s == 0) ? X0 : (s == 1) ? X1 : X2;
      row = (id & 2047) * 2 + r2;
      dst = Xb + (size_t)s * 4096 * 1040 + (size_t)row * 1040 + col;
    } else {
      const int s = (id - 6144) >> 9;
      src = (s == 0) ? W0 : (s == 1) ? W1 : (s == 2) ? W2 : W3;
      row = ((id - 6144) & 511) * 2 + r2;
      dst = Wb + (size_t)s * 1024 * 1040 + (size_t)row * 1040 + col;
    }
    *(ushort8v*)dst = load8(src, (size_t)row * 1024 + col, isf);
  } else {
    // mask [2][2048][2048] i32 -> bitmask [2*2048 rows][32 words] u64
    const int g    = (id - 8192) * 4 + (t >> 6);   // warp id, 4 words each
    const int lane = t & 63;
#pragma unroll
    for (int i = 0; i < 4; ++i) {
      const int wordId = g * 4 + i;                // 0..131071
      const int row  = wordId >> 5;
      const int word = wordId & 31;
      const int m = mask[(size_t)row * 2048 + word * 64 + lane];
      u64 bits = __ballot(m != 0);
      if (lane == 0) mpk[(size_t)row * 32 + word] = bits;
    }
  }
}

// mask pack standalone (fallback path only)
__global__ void pack_mask(const int* __restrict__ mask, u64* __restrict__ mpk) {
  const int gw   = (blockIdx.x * 256 + threadIdx.x) >> 6;
  const int lane = threadIdx.x & 63;
  const int word = gw & 31;
  const int row  = gw >> 5;
  const int m = mask[(size_t)row * 2048 + word * 64 + lane];
  u64 bits = __ballot(m != 0);
  if (lane == 0) mpk[(size_t)row * 32 + word] = bits;
}

// weights -> bf16 unpadded (fallback path only)
__global__ __launch_bounds__(256)
void cvt_w(const void* W0, const void* W1, const void* W2, const void* W3,
           u16* __restrict__ dst, const int* __restrict__ flagp) {
  const int isf = *flagp;
  const int z = blockIdx.y;
  const void* src = (z == 0) ? W0 : (z == 1) ? W1 : (z == 2) ? W2 : W3;
  const size_t off = ((size_t)blockIdx.x * 256 + threadIdx.x) * 8;
  *(ushort8v*)(dst + (size_t)z * 1024 * 1024 + off) = load8(src, off, isf);
}

// ---------------------------------------------------------------------------
// HOT QKV GEMM: double-buffered single-barrier pipeline (T3 minimal 2-phase).
// 128x128 tile, BK=32, LDS 32 KB (fused lS: lA | lB). Grid (32,8,3):
// blockIdx.x = tileM so the 8 N-blocks sharing an A-slice land on one XCD.
// z=0->Qb (x 0.125*log2e), z=1->Kb, z=2->Vt (transpose).
// GLOAD DMA staging for BOTH operands (r14 proved reg-staging regresses).
// z=2 transpose: per-wave PRIVATE 8KB regions, zero barriers.
// ---------------------------------------------------------------------------
__global__ __launch_bounds__(256, 3)
void gemm_qkv_b(const u16* __restrict__ Xb, const u16* __restrict__ Wb,
                u16* __restrict__ Qb, u16* __restrict__ Kb, u16* __restrict__ Vt)
{
  const int AS = 1040, WS = 1040, N = 1024, K = 1024;
  const int z = blockIdx.z;
  const u16* A = Xb + (size_t)z * 4096 * AS;
  const u16* W = Wb + (size_t)z * 1024 * WS;

  __shared__ __align__(16) u16 lS[4 * 128 * 32];   // 32KB: lA | lB
  u16* lA = lS;
  u16* lB = lS + 8192;

  const int tid  = threadIdx.x;
  const int lane = tid & 63;
  const int quad = lane >> 4;
  const int l15  = lane & 15;
  const int w    = tid >> 6;
  const int wm   = w >> 1, wn = w & 1;
  const int tileM = blockIdx.x * 128;
  const int tileN = blockIdx.y * 128;

  floatx4 acc[4][4] = {};

  const int ldRow = tid >> 2;        // 0..63
  const int ldCol = (tid & 3) * 8;   // 0,8,16,24
  const u16* aG = A + (size_t)(tileM + ldRow) * AS + ldCol;
  const u16* bG = W + (size_t)(tileN + ldRow) * WS + ldCol;
  u16* lAp = lA + tid * 8;           // wave-uniform base + lane*16B
  u16* lBp = lB + tid * 8;

  // prologue: stage tile 0 into buffer 0
  GLOAD_LDS16(aG, lAp);
  GLOAD_LDS16(aG + (size_t)64 * AS, lAp + 2048);
  GLOAD_LDS16(bG, lBp);
  GLOAD_LDS16(bG + (size_t)64 * WS, lBp + 2048);
  __syncthreads();

#pragma unroll 2
  for (int k0 = 0; k0 < K; k0 += 32) {
    const int cur = (k0 >> 5) & 1;
    const int nxo = 4096 * (cur ^ 1);
    if (k0 + 32 < K) {               // issue next tile's loads (stay in flight
      GLOAD_LDS16(aG + k0 + 32, lAp + nxo);                    // across compute)
      GLOAD_LDS16(aG + (size_t)64 * AS + k0 + 32, lAp + nxo + 2048);
      GLOAD_LDS16(bG + k0 + 32, lBp + nxo);
      GLOAD_LDS16(bG + (size_t)64 * WS + k0 + 32, lBp + nxo + 2048);
    }
    const u16* cA = lA + 4096 * cur;
    const u16* cB = lB + 4096 * cur;
    bf16x8 af[4], bw[4];
#pragma unroll
    for (int i = 0; i < 4; ++i) {
      af[i] = *(const bf16x8*)&cA[(wm * 64 + i * 16 + l15) * 32 + quad * 8];
      bw[i] = *(const bf16x8*)&cB[(wn * 64 + i * 16 + l15) * 32 + quad * 8];
    }
#pragma unroll
    for (int i = 0; i < 4; ++i)
#pragma unroll
      for (int j = 0; j < 4; ++j)
        acc[i][j] = __builtin_amdgcn_mfma_f32_16x16x32_bf16(af[i], bw[j], acc[i][j], 0, 0, 0);
    __syncthreads();                 // vmcnt(0) drain lands AFTER compute
  }

  if (z < 2) {
    u16* C = (z == 0) ? Qb : Kb;
    // z==0: fold 1/sqrt(Dh) * log2(e) into Q (attn uses exp2 directly)
    const float sc = (z == 0) ? 0.18033688011112042f : 1.0f;
#pragma unroll
    for (int i = 0; i < 4; ++i) {
      const int row0 = tileM + wm * 64 + i * 16 + quad * 4;
#pragma unroll
      for (int j = 0; j < 4; ++j) {
        const int col = tileN + wn * 64 + j * 16 + l15;
#pragma unroll
        for (int r = 0; r < 4; ++r)
          C[(size_t)(row0 + r) * N + col] = f2bf(acc[i][j][r] * sc);
      }
    }
  } else {
    // transpose 64x64 wave-tiles through PRIVATE LDS regions (XOR-swizzled).
    // All waves passed the K-loop's final barrier -> lS free; each wave
    // writes/reads ONLY its own 4096-u16 region -> no barriers at all.
    u16* myT = lS + w * 4096;
#pragma unroll
    for (int i = 0; i < 4; ++i)
#pragma unroll
      for (int j = 0; j < 4; ++j)
#pragma unroll
        for (int r = 0; r < 4; ++r) {
          const int lr = i * 16 + quad * 4 + r;
          const int lc = j * 16 + l15;
          myT[lr * 64 + (lc ^ (quad << 4))] = f2bf(acc[i][j][r]);
        }
    {
      const int n    = lane;
      const int gcol = tileN + wn * 64 + n;      // = h*64 + d
      const int hh = gcol >> 6, dd = gcol & 63;
      const int growBase = tileM + wm * 64;      // = b*2048 + s0
      const int bb = growBase >> 11;
      const int s0 = growBase & 2047;
      u16* dst = Vt + (((size_t)bb * 16 + hh) * 64 + dd) * 2048 + s0;
#pragma unroll
      for (int m0 = 0; m0 < 64; m0 += 8) {
        ushort8v pk;
#pragma unroll
        for (int t = 0; t < 8; ++t) {
          const int m = m0 + t;
          pk[t] = myT[m * 64 + (n ^ ((m & 12) << 2))];
        }
        *(ushort8v*)(dst + m0) = pk;
      }
    }
  }
}

// ---------------------------------------------------------------------------
// FALLBACK QKV GEMM: fp32/bf16 A via load8 + register prefetch, bf16 W
// (unpadded). Used only when ws_size is too small.
// ---------------------------------------------------------------------------
__global__ __launch_bounds__(256)
void gemm_qkv_f(const void* X0, const void* X1, const void* X2,
                const u16* __restrict__ Wb,
                u16* __restrict__ Qb, u16* __restrict__ Kb, u16* __restrict__ Vt,
                const int* __restrict__ flagp)
{
  const int K = 1024, N = 1024;
  const int isf = *flagp;
  const int z = blockIdx.z;
  const void* A_ = (z == 0) ? X0 : (z == 1) ? X1 : X2;
  const u16* W = Wb + (size_t)z * 1024 * 1024;

  __shared__ __align__(16) u16 lA[128 * 32];
  __shared__ __align__(16) u16 lB[128 * 32];

  const int tid  = threadIdx.x;
  const int lane = tid & 63;
  const int quad = lane >> 4;
  const int l15  = lane & 15;
  const int w    = tid >> 6;
  const int wm   = w >> 1, wn = w & 1;
  const int tileM = blockIdx.x * 128;
  const int tileN = blockIdx.y * 128;

  floatx4 acc[4][4] = {};

  const int ldRow = tid >> 2;
  const int ldCol = (tid & 3) * 8;
  const size_t aOff = (size_t)(tileM + ldRow) * K + ldCol;
  const u16* bG = W + (size_t)(tileN + ldRow) * K + ldCol;
  u16* lAp = lA + tid * 8;
  u16* lBp = lB + tid * 8;

  ushort8v a0 = load8(A_, aOff, isf);
  ushort8v a1 = load8(A_, aOff + (size_t)64 * K, isf);
  ushort8v b0 = *(const ushort8v*)bG;
  ushort8v b1 = *(const ushort8v*)(bG + (size_t)64 * K);

  for (int k0 = 0; k0 < K; k0 += 32) {
    __syncthreads();
    *(ushort8v*)lAp          = a0;
    *(ushort8v*)(lAp + 2048) = a1;
    *(ushort8v*)lBp          = b0;
    *(ushort8v*)(lBp + 2048) = b1;
    __syncthreads();

    if (k0 + 32 < K) {
      a0 = load8(A_, aOff + k0 + 32, isf);
      a1 = load8(A_, aOff + (size_t)64 * K + k0 + 32, isf);
      b0 = *(const ushort8v*)(bG + k0 + 32);
      b1 = *(const ushort8v*)(bG + (size_t)64 * K + k0 + 32);
    }

    bf16x8 af[4], bw[4];
#pragma unroll
    for (int i = 0; i < 4; ++i) {
      af[i] = *(const bf16x8*)&lA[(wm * 64 + i * 16 + l15) * 32 + quad * 8];
      bw[i] = *(const bf16x8*)&lB[(wn * 64 + i * 16 + l15) * 32 + quad * 8];
    }
#pragma unroll
    for (int i = 0; i < 4; ++i)
#pragma unroll
      for (int j = 0; j < 4; ++j)
        acc[i][j] = __builtin_amdgcn_mfma_f32_16x16x32_bf16(af[i], bw[j], acc[i][j], 0, 0, 0);
  }

  if (z < 2) {
    u16* C = (z == 0) ? Qb : Kb;
    const float sc = (z == 0) ? 0.18033688011112042f : 1.0f;
#pragma unroll
    for (int i = 0; i < 4; ++i) {
      const int row0 = tileM + wm * 64 + i * 16 + quad * 4;
#pragma unroll
      for (int j = 0; j < 4; ++j) {
        const int col = tileN + wn * 64 + j * 16 + l15;
#pragma unroll
        for (int r = 0; r < 4; ++r)
          C[(size_t)(row0 + r) * N + col] = f2bf(acc[i][j][r] * sc);
      }
    }
  } else {
    const int half = w >> 1;
    u16* myT = (w & 1) ? lB : lA;
#pragma unroll
    for (int pass = 0; pass < 2; ++pass) {
      __syncthreads();
      if (half == pass) {
#pragma unroll
        for (int i = 0; i < 4; ++i)
#pragma unroll
          for (int j = 0; j < 4; ++j)
#pragma unroll
            for (int r = 0; r < 4; ++r) {
              const int lr = i * 16 + quad * 4 + r;
              const int lc = j * 16 + l15;
              myT[lr * 64 + (lc ^ (quad << 4))] = f2bf(acc[i][j][r]);
            }
      }
      __syncthreads();
      if (half == pass) {
        const int n    = lane;
        const int gcol = tileN + wn * 64 + n;
        const int hh = gcol >> 6, dd = gcol & 63;
        const int growBase = tileM + wm * 64;
        const int bb = growBase >> 11;
        const int s0 = growBase & 2047;
        u16* dst = Vt + (((size_t)bb * 16 + hh) * 64 + dd) * 2048 + s0;
#pragma unroll
        for (int m0 = 0; m0 < 64; m0 += 8) {
          ushort8v pk;
#pragma unroll
          for (int t = 0; t < 8; ++t) {
            const int m = m0 + t;
            pk[t] = myT[m * 64 + (n ^ ((m & 12) << 2))];
          }
          *(ushort8v*)(dst + m0) = pk;
        }
      }
    }
  }
}

// ---------------------------------------------------------------------------
// Flash attention, no-max exp2 softmax. FROZEN at the r9/r10 plateau:
// QBLK=128, single barrier/kt, K/V dbuf, warp-private P. Six structures
// (2/1-barrier, QBLK 64/128, 8-32 waves/CU, setprio, pipelined-P) all land
// at 71+-3us (VALU ~50 / MFMA ~22) -> structural plateau for this family.
// ---------------------------------------------------------------------------
__global__ __launch_bounds__(256)
void attn(const u16* Qb, const u16* __restrict__ Kb, const u16* __restrict__ Vt,
          const u64* __restrict__ mpk, u16* AO, int aoStr)
{
  __shared__ __align__(16) u16 lK[2][64 * 64];
  __shared__ __align__(16) u16 lV[2][64 * 64];
  __shared__ __align__(16) u16 lP[4][32 * 64];

  const int tid  = threadIdx.x;
  const int lane = tid & 63;
  const int quad = lane >> 4;
  const int l15  = lane & 15;
  const int w    = tid >> 6;

  const int bh = blockIdx.x;
  const int qt = blockIdx.y;
  const int b  = bh >> 4;
  const int h  = bh & 15;
  const size_t rowB   = (size_t)b * 2048;
  const size_t vtBase = ((size_t)bh * 64) * 2048;
  const int qbase = qt * 128 + w * 32;     // this warp's 32 q-rows

  bf16x8 aq[2][2];                         // [q-group][k-half]
#pragma unroll
  for (int g = 0; g < 2; ++g) {
    const u16* qp = Qb + (rowB + qbase + g * 16 + l15) * 1024 + h * 64 + quad * 8;
    aq[g][0] = *(const bf16x8*)qp;
    aq[g][1] = *(const bf16x8*)(qp + 32);
  }

  const ushort8v one_u = {0x3F80, 0x3F80, 0x3F80, 0x3F80, 0x3F80, 0x3F80, 0x3F80, 0x3F80};
  const bf16x8 ones = __builtin_bit_cast(bf16x8, one_u);

  floatx4 o[2][4];
  floatx4 l4[2];
#pragma unroll
  for (int g = 0; g < 2; ++g) {
    l4[g] = (floatx4){0.f, 0.f, 0.f, 0.f};
#pragma unroll
    for (int nb = 0; nb < 4; ++nb) o[g][nb] = (floatx4){0.f, 0.f, 0.f, 0.f};
  }

  // swapped QK^T: lane's q-rows are qbase + g*16 + l15 -> one mask word per g
  const u64* mrow0 = mpk + (rowB + qbase + l15) * 32;
  const u64* mrow1 = mpk + (rowB + qbase + 16 + l15) * 32;
  u16* lPw = &lP[w][0];              // per-warp [32 q][64 k]

  // staging: row = tid>>3, col16 = tid&7; source col pre-XOR'd so swizzled
  // reads see logical LDS[r][c] = M[r][c ^ ((r&7)<<3)] (u16 units).
  const int r1 = tid >> 3;
  const int cs = ((tid & 7) ^ (r1 & 7)) * 8;
  const u16* kSrc = Kb + (rowB + r1) * 1024 + h * 64 + cs;
  const u16* vSrc = Vt + vtBase + (size_t)r1 * 2048 + cs;

  // prologue: K(0),V(0) -> buffer 0 (drained by the kt=0 barrier)
  GLOAD_LDS16(kSrc,                     &lK[0][tid * 8]);
  GLOAD_LDS16(kSrc + (size_t)32 * 1024, &lK[0][tid * 8 + 2048]);
  GLOAD_LDS16(vSrc,                     &lV[0][tid * 8]);
  GLOAD_LDS16(vSrc + (size_t)32 * 2048, &lV[0][tid * 8 + 2048]);

#pragma unroll 2
  for (int kt = 0; kt < 32; ++kt) {
    const int cur = kt & 1;
    __syncthreads();                 // drains buf[cur] DMA; all waves finished
                                     // reading buf[cur^1] last iter -> WAR safe
    if (kt < 31) {                   // prefetch kt+1; lands during this compute
      const u16* kS = kSrc + (size_t)(kt + 1) * 64 * 1024;
      const u16* vS = vSrc + (kt + 1) * 64;
      GLOAD_LDS16(kS,                     &lK[cur ^ 1][tid * 8]);
      GLOAD_LDS16(kS + (size_t)32 * 1024, &lK[cur ^ 1][tid * 8 + 2048]);
      GLOAD_LDS16(vS,                     &lV[cur ^ 1][tid * 8]);
      GLOAD_LDS16(vS + (size_t)32 * 2048, &lV[cur ^ 1][tid * 8 + 2048]);
    }

    const u64 mw0 = mrow0[kt];
    const u64 mw1 = mrow1[kt];

#pragma unroll
    for (int nb = 0; nb < 4; ++nb) {
      const int row = nb * 16 + l15;
      const int swk = (row & 7) << 3;
      // A = K rows (shared across both q-groups), B = Q (registers)
      bf16x8 ak0 = *(const bf16x8*)&lK[cur][row * 64 + ((quad * 8) ^ swk)];
      bf16x8 ak1 = *(const bf16x8*)&lK[cur][row * 64 + ((quad * 8 + 32) ^ swk)];
      floatx4 s0 = {0.f, 0.f, 0.f, 0.f};
      floatx4 s1 = {0.f, 0.f, 0.f, 0.f};
      s0 = __builtin_amdgcn_mfma_f32_16x16x32_bf16(ak0, aq[0][0], s0, 0, 0, 0);
      s1 = __builtin_amdgcn_mfma_f32_16x16x32_bf16(ak0, aq[1][0], s1, 0, 0, 0);
      s0 = __builtin_amdgcn_mfma_f32_16x16x32_bf16(ak1, aq[0][1], s0, 0, 0, 0);
      s1 = __builtin_amdgcn_mfma_f32_16x16x32_bf16(ak1, aq[1][1], s1, 0, 0, 0);
      // S^T[k = nb*16+quad*4+r][q]; mask bits are k-consecutive
      const int kb = nb * 16 + quad * 4;
      const uint32_t nib0 = (uint32_t)(mw0 >> kb) & 0xFu;
      const uint32_t nib1 = (uint32_t)(mw1 >> kb) & 0xFu;
      const float a0 = (nib0 & 1u) ? __builtin_amdgcn_exp2f(s0[0]) : 0.0f;
      const float a1 = (nib0 & 2u) ? __builtin_amdgcn_exp2f(s0[1]) : 0.0f;
      const float a2 = (nib0 & 4u) ? __builtin_amdgcn_exp2f(s0[2]) : 0.0f;
      const float a3 = (nib0 & 8u) ? __builtin_amdgcn_exp2f(s0[3]) : 0.0f;
      const float c0 = (nib1 & 1u) ? __builtin_amdgcn_exp2f(s1[0]) : 0.0f;
      const float c1 = (nib1 & 2u) ? __builtin_amdgcn_exp2f(s1[1]) : 0.0f;
      const float c2 = (nib1 & 4u) ? __builtin_amdgcn_exp2f(s1[2]) : 0.0f;
      const float c3 = (nib1 & 8u) ? __builtin_amdgcn_exp2f(s1[3]) : 0.0f;
      bf16x4 p0, p1;
      p0[0] = (__bf16)a0; p0[1] = (__bf16)a1;   // v_cvt_pk_bf16_f32 (RNE)
      p0[2] = (__bf16)a2; p0[3] = (__bf16)a3;
      p1[0] = (__bf16)c0; p1[1] = (__bf16)c1;
      p1[2] = (__bf16)c2; p1[3] = (__bf16)c3;
      const int col = kb ^ ((l15 & 7) << 3);
      *(bf16x4*)&lPw[l15 * 64 + col]        = p0;   // ds_write_b64
      *(bf16x4*)&lPw[(16 + l15) * 64 + col] = p1;
    }
    // no barrier: P is warp-private; same-wave DS ordering covers write->read

#pragma unroll
    for (int ks = 0; ks < 2; ++ks) {
      const int pc = (ks * 32 + quad * 8) ^ ((l15 & 7) << 3);
      bf16x8 ap0 = *(const bf16x8*)&lPw[l15 * 64 + pc];
      bf16x8 ap1 = *(const bf16x8*)&lPw[(16 + l15) * 64 + pc];
#pragma unroll
      for (int nb = 0; nb < 4; ++nb) {
        const int row = nb * 16 + l15;
        bf16x8 bv = *(const bf16x8*)&lV[cur][row * 64 + ((ks * 32 + quad * 8) ^ ((row & 7) << 3))];
        o[0][nb] = __builtin_amdgcn_mfma_f32_16x16x32_bf16(ap0, bv, o[0][nb], 0, 0, 0);
        o[1][nb] = __builtin_amdgcn_mfma_f32_16x16x32_bf16(ap1, bv, o[1][nb], 0, 0, 0);
      }
      l4[0] = __builtin_amdgcn_mfma_f32_16x16x32_bf16(ap0, ones, l4[0], 0, 0, 0);
      l4[1] = __builtin_amdgcn_mfma_f32_16x16x32_bf16(ap1, ones, l4[1], 0, 0, 0);
    }
  }

#pragma unroll
  for (int g = 0; g < 2; ++g)
#pragma unroll
    for (int r = 0; r < 4; ++r) {
      const float inv = 1.0f / l4[g][r];
      const size_t orow = (rowB + qbase + g * 16 + quad * 4 + r) * aoStr + h * 64;
#pragma unroll
      for (int nb = 0; nb < 4; ++nb)
        AO[orow + nb * 16 + l15] = f2bf(o[g][nb][r] * inv);
    }
}

// ---------------------------------------------------------------------------
// Output projection: 64x64 tile, grid (64,16) = 1024 blocks = 4 blocks/CU.
// Latency-bound 2-phase kernel; same-x blocks share the A panel and land on
// one XCD (linear id = x + 64y => id mod 8 == x mod 8) -> L2 A-reuse.
// ---------------------------------------------------------------------------
__global__ __launch_bounds__(256, 4)
void gemm_out(const u16* __restrict__ A, int aStr,
              const u16* __restrict__ W, int wStr, void* C_,
              const int* __restrict__ flagp)
{
  const int K = 1024, N = 1024;
  const int isf = *flagp;

  __shared__ __align__(16) u16 lA[2 * 64 * 32];
  __shared__ __align__(16) u16 lB[2 * 64 * 32];

  const int tid  = threadIdx.x;
  const int lane = tid & 63;
  const int quad = lane >> 4;
  const int l15  = lane & 15;
  const int w    = tid >> 6;
  const int tileM = blockIdx.x * 64;
  const int tileN = blockIdx.y * 64;

  floatx4 acc[4] = {};

  const int ldRow = tid >> 2;
  const int ldCol = (tid & 3) * 8;
  const u16* aG = A + (size_t)(tileM + ldRow) * aStr + ldCol;
  const u16* bG = W + (size_t)(tileN + ldRow) * wStr + ldCol;
  u16* lAp = lA + tid * 8;
  u16* lBp = lB + tid * 8;

  // prologue: stage tile 0 into buffer 0
  GLOAD_LDS16(aG, lAp);
  GLOAD_LDS16(bG, lBp);
  __syncthreads();

#pragma unroll 2
  for (int k0 = 0; k0 < K; k0 += 32) {
    const int cur = (k0 >> 5) & 1;
    const int nx = 2048 * (cur ^ 1);
    if (k0 + 32 < K) {
      GLOAD_LDS16(aG + k0 + 32, lAp + nx);
      GLOAD_LDS16(bG + k0 + 32, lBp + nx);
    }
    const u16* cA = lA + 2048 * cur;
    const u16* cB = lB + 2048 * cur;
    bf16x8 af[4], bw;
#pragma unroll
    for (int i = 0; i < 4; ++i)
      af[i] = *(const bf16x8*)&cA[(i * 16 + l15) * 32 + quad * 8];
    bw = *(const bf16x8*)&cB[(w * 16 + l15) * 32 + quad * 8];
#pragma unroll
    for (int i = 0; i < 4; ++i)
      acc[i] = __builtin_amdgcn_mfma_f32_16x16x32_bf16(af[i], bw, acc[i], 0, 0, 0);
    __syncthreads();
  }

#pragma unroll
  for (int i = 0; i < 4; ++i) {
    const int row0 = tileM + i * 16 + quad * 4;
    const int col  = tileN + w * 16 + l15;
#pragma unroll
    for (int r = 0; r < 4; ++r) {
      const size_t off = (size_t)(row0 + r) * N + col;
      if (isf) ((float*)C_)[off] = acc[i][r];
      else     ((u16*)C_)[off]   = f2bf(acc[i][r]);
    }
  }
}

// ---------------------------------------------------------------------------
extern "C" void kernel_launch(void* const* d_in, const int* in_sizes, int n_in,
                              void* d_out, int out_size, void* d_ws, size_t ws_size,
                              hipStream_t stream)
{
  const int* mk = (const int*)d_in[3];

  // ws: [flag 256B][mpk 1MB][Qb 8MB][Kb 8MB][Vt 8MB][Wb pad 8.5MB][Xb pad 25.6MB]
  int* flag = (int*)d_ws;
  u64* mpk  = (u64*)((char*)d_ws + 256);
  const size_t SZ = (size_t)4096 * 1024;
  u16* Qb = (u16*)((char*)d_ws + 256 + (size_t)1048576);
  u16* Kb = Qb + SZ;
  u16* Vt = Kb + SZ;
  u16* Wb = Vt + SZ;

  const size_t WB_PAD = (size_t)4 * 1024 * 1040;
  const size_t XB_PAD = (size_t)3 * 4096 * 1040;
  const size_t NEED = 256 + 1048576 + 3 * SZ * 2 + WB_PAD * 2 + XB_PAD * 2;

  if (ws_size >= NEED) {
    // HOT PATH: 4 dispatches. prep fuses cvt + mask-pack + dtype detect.
    u16* Xb = Wb + WB_PAD;
    prep<<<16384, 256, 0, stream>>>(d_in[0], d_in[1], d_in[2],
                                    d_in[4], d_in[5], d_in[6], d_in[7],
                                    Xb, Wb, mk, mpk, flag);
    gemm_qkv_b<<<dim3(32, 8, 3), 256, 0, stream>>>(Xb, Wb, Qb, Kb, Vt);
    u16* AOp = Xb;  // Xb consumed; reuse slot 0 (4096 x 1040) for attn output
    attn<<<dim3(32, 16), 256, 0, stream>>>(Qb, Kb, Vt, mpk, AOp, 1040);
    gemm_out<<<dim3(64, 16), 256, 0, stream>>>(AOp, 1040,
                                               Wb + (size_t)3 * 1024 * 1040, 1040,
                                               d_out, flag);
  } else {
    // FALLBACK (proven at 33.3 MB ws)
    detect_dtype<<<1, 256, 0, stream>>>((const u16*)d_in[0], flag);
    pack_mask<<<32768, 256, 0, stream>>>(mk, mpk);
    cvt_w<<<dim3(512, 4), 256, 0, stream>>>(d_in[4], d_in[5], d_in[6], d_in[7], Wb, flag);
    gemm_qkv_f<<<dim3(32, 8, 3), 256, 0, stream>>>(d_in[0], d_in[1], d_in[2],
                                                   Wb, Qb, Kb, Vt, flag);
    attn<<<dim3(32, 16), 256, 0, stream>>>(Qb, Kb, Vt, mpk, Qb, 1024);
    gemm_out<<<dim3(64, 16), 256, 0, stream>>>(Qb, 1024,
                                               Wb + (size_t)3 * 1024 * 1024, 1024,
                                               d_out, flag);
  }
}